// Round 14
// baseline (536.882 us; speedup 1.0000x reference)
//
#include <hip/hip_runtime.h>
#include <hip/hip_fp16.h>

// Problem constants (fixed by setup_inputs)
#define E_TOTAL 524288
#define RRELU_SLOPE 0.22916666666666666f
#define NKSPLIT 10

typedef float f32x4 __attribute__((ext_vector_type(4)));
typedef short short8_t __attribute__((ext_vector_type(8)));
typedef _Float16 half4_t __attribute__((ext_vector_type(4)));
typedef _Float16 h2v __attribute__((ext_vector_type(2)));

// Direct builtin call (host pass defers diagnostics for target builtins
// inside __global__ bodies — round-3 lesson: no host-side stubs/guards).
#define MFMA16F16 __builtin_amdgcn_mfma_f32_16x16x16f16

#if defined(__HIP_DEVICE_COMPILE__)
# if __has_builtin(__builtin_amdgcn_cvt_pkrtz)
#  define HAVE_PKRTZ 1
# endif
#endif

__device__ inline unsigned short f2bf(float x) {
  unsigned int u = __float_as_uint(x);
  u += 0x7FFFu + ((u >> 16) & 1u);   // RNE
  return (unsigned short)(u >> 16);
}

__device__ inline unsigned int pack_h2(float a, float b) {
  __half2 h = __floats2half2_rn(a, b);
  return __builtin_bit_cast(unsigned int, h);
}

__device__ inline unsigned int pack_h2_fast(float a, float b) {
#ifdef HAVE_PKRTZ
  return __builtin_bit_cast(unsigned int, __builtin_amdgcn_cvt_pkrtz(a, b));
#else
  return pack_h2(a, b);
#endif
}

// ---------------------------------------------------------------------------
// Generic bf16-MFMA GEMM (fp32 A), dual parameter set via blockIdx.z.
// C[M,N] = act(A @ B + bias). If Ch != null, write bf16 output instead of C.
// Grid: (M/128, N/128, 2). act: 0=none, 2=rrelu
// ---------------------------------------------------------------------------
__global__ __launch_bounds__(256) void gemm_bf16_dual(
    const float* __restrict__ A1, const unsigned short* __restrict__ BT1,
    const float* __restrict__ bias1, float* __restrict__ C1,
    unsigned short* __restrict__ Ch1,
    const float* __restrict__ A2, const unsigned short* __restrict__ BT2,
    const float* __restrict__ bias2, float* __restrict__ C2,
    unsigned short* __restrict__ Ch2,
    int lda, int ldc, int K, int act)
{
  const float* A = blockIdx.z ? A2 : A1;
  const unsigned short* BT = blockIdx.z ? BT2 : BT1;
  const float* bias = blockIdx.z ? bias2 : bias1;
  float* C = blockIdx.z ? C2 : C1;
  unsigned short* Ch = blockIdx.z ? Ch2 : Ch1;

  __shared__ unsigned short As[128][32];
  __shared__ unsigned short Bs[128][32];
  const int tid = threadIdx.x;
  const int bm = blockIdx.x, bn = blockIdx.y;
  const int w = tid >> 6, l = tid & 63;
  const int wm = (w & 1) * 64, wn = (w >> 1) * 64;
  const int q = l >> 4, r = l & 15;

  f32x4 acc[4][4];
  for (int i = 0; i < 4; ++i)
    for (int j = 0; j < 4; ++j)
      acc[i][j] = (f32x4){0.f, 0.f, 0.f, 0.f};

  const int sm = tid >> 1;
  const int sk = (tid & 1) * 16;
  const float* ap = A + (size_t)(bm * 128 + sm) * lda + sk;
  const unsigned short* bp = BT + (size_t)(bn * 128 + sm) * K + sk;

  for (int k0 = 0; k0 < K; k0 += 32) {
    float4 f0 = *(const float4*)(ap + k0);
    float4 f1 = *(const float4*)(ap + k0 + 4);
    float4 f2 = *(const float4*)(ap + k0 + 8);
    float4 f3 = *(const float4*)(ap + k0 + 12);
    uint4 p0, p1;
    p0.x = (unsigned)f2bf(f0.x) | ((unsigned)f2bf(f0.y) << 16);
    p0.y = (unsigned)f2bf(f0.z) | ((unsigned)f2bf(f0.w) << 16);
    p0.z = (unsigned)f2bf(f1.x) | ((unsigned)f2bf(f1.y) << 16);
    p0.w = (unsigned)f2bf(f1.z) | ((unsigned)f2bf(f1.w) << 16);
    p1.x = (unsigned)f2bf(f2.x) | ((unsigned)f2bf(f2.y) << 16);
    p1.y = (unsigned)f2bf(f2.z) | ((unsigned)f2bf(f2.w) << 16);
    p1.z = (unsigned)f2bf(f3.x) | ((unsigned)f2bf(f3.y) << 16);
    p1.w = (unsigned)f2bf(f3.z) | ((unsigned)f2bf(f3.w) << 16);
    *(uint4*)&As[sm][sk] = p0;
    *(uint4*)&As[sm][sk + 8] = p1;
    uint4 b0 = *(const uint4*)(bp + k0);
    uint4 b1 = *(const uint4*)(bp + k0 + 8);
    *(uint4*)&Bs[sm][sk] = b0;
    *(uint4*)&Bs[sm][sk + 8] = b1;
    __syncthreads();

    short8_t af[4], bfr[4];
    for (int mt = 0; mt < 4; ++mt)
      af[mt] = *(const short8_t*)&As[wm + mt * 16 + r][q * 8];
    for (int nt = 0; nt < 4; ++nt)
      bfr[nt] = *(const short8_t*)&Bs[wn + nt * 16 + r][q * 8];
    for (int mt = 0; mt < 4; ++mt)
      for (int nt = 0; nt < 4; ++nt)
        acc[mt][nt] = __builtin_amdgcn_mfma_f32_16x16x32_bf16(
            af[mt], bfr[nt], acc[mt][nt], 0, 0, 0);
    __syncthreads();
  }

  for (int nt = 0; nt < 4; ++nt) {
    int gc = bn * 128 + wn + nt * 16 + r;
    float bv = bias ? bias[gc] : 0.f;
    for (int mt = 0; mt < 4; ++mt) {
      int gm = bm * 128 + wm + mt * 16 + q * 4;
      for (int rr = 0; rr < 4; ++rr) {
        float v = acc[mt][nt][rr] + bv;
        if (act == 2) v = (v >= 0.f) ? v : v * RRELU_SLOPE;
        if (Ch) Ch[(size_t)(gm + rr) * ldc + gc] = f2bf(v);
        else    C[(size_t)(gm + rr) * ldc + gc] = v;
      }
    }
  }
}

// ---------------------------------------------------------------------------
// y-GEMM (bf16 A): y[M,512] = A @ Wcat + bcat, dual via blockIdx.z.
// Grid (128,4,2). Output split:
//  bn 0,1 (cols 0..255, message half): packed fp16 pair-dwords
//    yp[row*128 + bn*64 + j] = h2(y[bn*128+j], y[bn*128+j+64]), j in [0,64).
//  bn 2,3 (cols 256..511, self half): fp32 to y2[row*256 + col].
// Staging via global_load_lds width=16.
// ---------------------------------------------------------------------------
__global__ __launch_bounds__(256) void gemm_h_dual(
    const unsigned short* __restrict__ Ah1, const unsigned short* __restrict__ BT1,
    const float* __restrict__ bias1, unsigned int* __restrict__ yp1,
    float* __restrict__ y2o1,
    const unsigned short* __restrict__ Ah2, const unsigned short* __restrict__ BT2,
    const float* __restrict__ bias2, unsigned int* __restrict__ yp2,
    float* __restrict__ y2o2,
    int K)
{
  const unsigned short* A = blockIdx.z ? Ah2 : Ah1;
  const unsigned short* BT = blockIdx.z ? BT2 : BT1;
  const float* bias = blockIdx.z ? bias2 : bias1;
  unsigned int* yp = blockIdx.z ? yp2 : yp1;
  float* y2o = blockIdx.z ? y2o2 : y2o1;

  __shared__ unsigned short As[128][32];
  __shared__ unsigned short Bs[128][32];
  const int tid = threadIdx.x;
  const int bm = blockIdx.x, bn = blockIdx.y;
  const int w = tid >> 6, l = tid & 63;
  const int wm = (w & 1) * 64;
  const int q = l >> 4, r = l & 15;
  const bool packed = bn < 2;
  const int wn2 = (w >> 1) * 32;     // packed-mode col base
  const int wn = (w >> 1) * 64;      // plain-mode col base

  // col-within-block of tile nt for this wave
  int colb[4];
#pragma unroll
  for (int nt = 0; nt < 4; ++nt)
    colb[nt] = packed ? (wn2 + (nt & 1) * 16 + (nt >> 1) * 64) : (wn + nt * 16);

  f32x4 acc[4][4];
  for (int i = 0; i < 4; ++i)
    for (int j = 0; j < 4; ++j)
      acc[i][j] = (f32x4){0.f, 0.f, 0.f, 0.f};

  const int gr = l >> 2;          // row within 16-row chunk
  const int gk = (l & 3) * 8;     // short offset within K-tile of 32
  const unsigned short* aw = A + (size_t)(bm * 128 + w * 32 + gr) * K + gk;
  const unsigned short* bw = BT + (size_t)(bn * 128 + w * 32 + gr) * K + gk;

  for (int k0 = 0; k0 < K; k0 += 32) {
    __builtin_amdgcn_global_load_lds(
        (const __attribute__((address_space(1))) unsigned int*)(aw + k0),
        (__attribute__((address_space(3))) unsigned int*)&As[w * 32][0], 16, 0, 0);
    __builtin_amdgcn_global_load_lds(
        (const __attribute__((address_space(1))) unsigned int*)(aw + (size_t)16 * K + k0),
        (__attribute__((address_space(3))) unsigned int*)&As[w * 32 + 16][0], 16, 0, 0);
    __builtin_amdgcn_global_load_lds(
        (const __attribute__((address_space(1))) unsigned int*)(bw + k0),
        (__attribute__((address_space(3))) unsigned int*)&Bs[w * 32][0], 16, 0, 0);
    __builtin_amdgcn_global_load_lds(
        (const __attribute__((address_space(1))) unsigned int*)(bw + (size_t)16 * K + k0),
        (__attribute__((address_space(3))) unsigned int*)&Bs[w * 32 + 16][0], 16, 0, 0);
    __syncthreads();

    short8_t af[4], bfr[4];
    for (int mt = 0; mt < 4; ++mt)
      af[mt] = *(const short8_t*)&As[wm + mt * 16 + r][q * 8];
    for (int nt = 0; nt < 4; ++nt)
      bfr[nt] = *(const short8_t*)&Bs[colb[nt] + r][q * 8];
    for (int mt = 0; mt < 4; ++mt)
      for (int nt = 0; nt < 4; ++nt)
        acc[mt][nt] = __builtin_amdgcn_mfma_f32_16x16x32_bf16(
            af[mt], bfr[nt], acc[mt][nt], 0, 0, 0);
    __syncthreads();
  }

  if (packed) {
    for (int nt2 = 0; nt2 < 2; ++nt2) {
      int j = wn2 + nt2 * 16 + r;              // dword idx in [0,64)
      float blo = bias[bn * 128 + j];
      float bhi = bias[bn * 128 + j + 64];
      for (int mt = 0; mt < 4; ++mt) {
        int gm = bm * 128 + wm + mt * 16 + q * 4;
        for (int rr = 0; rr < 4; ++rr) {
          float lo = acc[mt][nt2][rr] + blo;
          float hi = acc[mt][nt2 + 2][rr] + bhi;
          yp[(size_t)(gm + rr) * 128 + bn * 64 + j] = pack_h2_fast(lo, hi);
        }
      }
    }
  } else {
    for (int nt = 0; nt < 4; ++nt) {
      int col = (bn - 2) * 128 + wn + nt * 16 + r;   // in [0,256)
      float bv = bias[256 + col];
      for (int mt = 0; mt < 4; ++mt) {
        int gm = bm * 128 + wm + mt * 16 + q * 4;
        for (int rr = 0; rr < 4; ++rr)
          y2o[(size_t)(gm + rr) * 256 + col] = acc[mt][nt][rr] + bv;
      }
    }
  }
}

// ---------------------------------------------------------------------------
// Split-K readout GEMM: P[kc][M=256][N=256] += A[256][1280] @ BT[256][1280]^T
// per K-chunk of 128. Grid (4,4,2*NKSPLIT): z = mol | kc<<1.
// ---------------------------------------------------------------------------
__global__ __launch_bounds__(256) void gemm_splitk_dual(
    const float* __restrict__ A1, const unsigned short* __restrict__ BT1,
    float* __restrict__ P1,
    const float* __restrict__ A2, const unsigned short* __restrict__ BT2,
    float* __restrict__ P2)
{
  const int mol = blockIdx.z & 1;
  const int kc = blockIdx.z >> 1;
  const float* A = mol ? A2 : A1;
  const unsigned short* BT = mol ? BT2 : BT1;
  float* P = mol ? P2 : P1;
  const int K = 1280;

  __shared__ unsigned short As[64][32];
  __shared__ unsigned short Bs[64][32];
  const int tid = threadIdx.x;
  const int m0 = blockIdx.x * 64, n0 = blockIdx.y * 64;
  const int w = tid >> 6, l = tid & 63;
  const int wm = (w & 1) * 32, wn = (w >> 1) * 32;
  const int q = l >> 4, r = l & 15;

  f32x4 acc[2][2];
  for (int i = 0; i < 2; ++i)
    for (int j = 0; j < 2; ++j)
      acc[i][j] = (f32x4){0.f, 0.f, 0.f, 0.f};

  const int sm = tid >> 2;        // 0..63
  const int sk = (tid & 3) * 8;   // 0,8,16,24
  const float* ap = A + (size_t)(m0 + sm) * K + kc * 128 + sk;
  const unsigned short* bp = BT + (size_t)(n0 + sm) * K + kc * 128 + sk;

  for (int k0 = 0; k0 < 128; k0 += 32) {
    float4 f0 = *(const float4*)(ap + k0);
    float4 f1 = *(const float4*)(ap + k0 + 4);
    uint4 p0;
    p0.x = (unsigned)f2bf(f0.x) | ((unsigned)f2bf(f0.y) << 16);
    p0.y = (unsigned)f2bf(f0.z) | ((unsigned)f2bf(f0.w) << 16);
    p0.z = (unsigned)f2bf(f1.x) | ((unsigned)f2bf(f1.y) << 16);
    p0.w = (unsigned)f2bf(f1.z) | ((unsigned)f2bf(f1.w) << 16);
    *(uint4*)&As[sm][sk] = p0;
    *(uint4*)&Bs[sm][sk] = *(const uint4*)(bp + k0);
    __syncthreads();

    short8_t af[2], bfr[2];
    for (int mt = 0; mt < 2; ++mt)
      af[mt] = *(const short8_t*)&As[wm + mt * 16 + r][q * 8];
    for (int nt = 0; nt < 2; ++nt)
      bfr[nt] = *(const short8_t*)&Bs[wn + nt * 16 + r][q * 8];
    for (int mt = 0; mt < 2; ++mt)
      for (int nt = 0; nt < 2; ++nt)
        acc[mt][nt] = __builtin_amdgcn_mfma_f32_16x16x32_bf16(
            af[mt], bfr[nt], acc[mt][nt], 0, 0, 0);
    __syncthreads();
  }

  for (int nt = 0; nt < 2; ++nt) {
    int gc = n0 + wn + nt * 16 + r;
    for (int mt = 0; mt < 2; ++mt) {
      int gm = m0 + wm + mt * 16 + q * 4;
      for (int rr = 0; rr < 4; ++rr)
        P[((size_t)kc * 256 + gm + rr) * 256 + gc] = acc[mt][nt][rr];
    }
  }
}

// ---------------------------------------------------------------------------
// Per-graph counting sort of edges by destination node (dual-mol grid 512).
// ---------------------------------------------------------------------------
__global__ __launch_bounds__(256) void sort_edges_dual(
    const int* __restrict__ ei1, const int* __restrict__ ei2,
    int* __restrict__ meta1, int* __restrict__ meta2,
    int* __restrict__ perm1, int* __restrict__ perm2,
    int* __restrict__ starts1, int* __restrict__ starts2)
{
  const int mol = blockIdx.x >> 8;
  const int g = blockIdx.x & 255;
  const int* eidx = mol ? ei2 : ei1;
  int* meta = mol ? meta2 : meta1;
  int* perm = mol ? perm2 : perm1;
  int* starts = mol ? starts2 : starts1;

  __shared__ int cnt[4][64];
  __shared__ int startS[65];
  __shared__ int cur[64];
  const int t = threadIdx.x, w = t >> 6;
  cnt[w][t & 63] = 0;
  if (t < 64) cur[t] = 0;
  __syncthreads();
  for (int i = t; i < 2048; i += 256)
    atomicAdd(&cnt[w][eidx[E_TOTAL + g * 2048 + i] & 63], 1);
  __syncthreads();
  if (t == 0) {
    int acc = 0;
    for (int n = 0; n < 64; ++n) {
      startS[n] = acc;
      acc += cnt[0][n] + cnt[1][n] + cnt[2][n] + cnt[3][n];
    }
    startS[64] = acc;
  }
  __syncthreads();
  if (t < 65) starts[g * 65 + t] = startS[t];
  for (int i = t; i < 2048; i += 256) {
    int s = eidx[g * 2048 + i] & 63;
    int d = eidx[E_TOTAL + g * 2048 + i] & 63;
    int p = startS[d] + atomicAdd(&cur[d], 1);
    meta[g * 2048 + p] = s | (d << 8);
    perm[g * 2048 + p] = i;
  }
}

// ---------------------------------------------------------------------------
// Gather ea through sort permutation, pack to 8 half2 dwords (dual, grid 4096)
// ---------------------------------------------------------------------------
__global__ __launch_bounds__(256) void ea_gather_pack_dual(
    const float* __restrict__ ea1, const float* __restrict__ ea2,
    const int* __restrict__ perm1, const int* __restrict__ perm2,
    unsigned int* __restrict__ o1, unsigned int* __restrict__ o2)
{
  const int mol = blockIdx.x >> 11;
  const float* ea = mol ? ea2 : ea1;
  const int* perm = mol ? perm2 : perm1;
  unsigned int* out = mol ? o2 : o1;
  int p = (blockIdx.x & 2047) * 256 + threadIdx.x;  // 0..E-1
  int g = p >> 11;
  int i = perm[p];
  const float* s = ea + (size_t)(g * 2048 + i) * 16;
  float4 v0 = *(const float4*)(s);
  float4 v1 = *(const float4*)(s + 4);
  float4 v2 = *(const float4*)(s + 8);
  float4 v3 = *(const float4*)(s + 12);
  uint4 q0, q1;
  q0.x = pack_h2(v0.x, v0.y); q0.y = pack_h2(v0.z, v0.w);
  q0.z = pack_h2(v1.x, v1.y); q0.w = pack_h2(v1.z, v1.w);
  q1.x = pack_h2(v2.x, v2.y); q1.y = pack_h2(v2.z, v2.w);
  q1.z = pack_h2(v3.x, v3.y); q1.w = pack_h2(v3.z, v3.w);
  *(uint4*)(out + (size_t)p * 8) = q0;
  *(uint4*)(out + (size_t)p * 8 + 4) = q1;
}

// ---------------------------------------------------------------------------
// Edge conv v16: both 64-dim halves merged into one block (was 2 blocks per
// graph). Per-edge machinery — meta load, 4x ds_bpermute, indicator build,
// prefetch, loop control — now paid ONCE per edge instead of twice, and the
// 17MB eas array is fetched once per dispatch. Grid (256,1,2), 512 blocks =
// exactly 2/CU resident. acc[2][8], bfr[2][8]; ypk holds both halves
// (33.3KB LDS). Core msg/MFMA structure is the round-12 verified one.
// WR32 compile-time (round 9-11 lesson: no runtime flags in epilogue).
// ---------------------------------------------------------------------------
template <bool WR32>
__device__ __forceinline__ void edge_conv_body(
    const unsigned int* __restrict__ ypA, const float* __restrict__ y2A,
    const int* __restrict__ meta1,
    const unsigned int* __restrict__ eas1, const unsigned int* __restrict__ wep1,
    const int* __restrict__ st1, float* __restrict__ xo1,
    unsigned short* __restrict__ xoh1,
    const unsigned int* __restrict__ ypB, const float* __restrict__ y2B,
    const int* __restrict__ meta2,
    const unsigned int* __restrict__ eas2, const unsigned int* __restrict__ wep2,
    const int* __restrict__ st2, float* __restrict__ xo2,
    unsigned short* __restrict__ xoh2)
{
  const unsigned int* yp; const float* y2; const int* meta;
  const unsigned int* eas; const unsigned int* wep; const int* st;
  float* xo; unsigned short* xoh;
  if (blockIdx.z == 0) { yp = ypA; y2 = y2A; meta = meta1; eas = eas1; wep = wep1; st = st1; xo = xo1; xoh = xoh1; }
  else                 { yp = ypB; y2 = y2B; meta = meta2; eas = eas2; wep = wep2; st = st2; xo = xo2; xoh = xoh2; }

  __shared__ unsigned int ypk[8320];   // 33.3 KB: [half][node][j] stride 65
  const int g = blockIdx.x;            // graph 0..255
  const int tid = threadIdx.x;
  const int l = tid & 63;
  const int w = tid >> 6;       // wave owns nodes [8w, 8w+8)
  const int rh = l & 15;        // MFMA row/col lane coord
  const int qh = l >> 4;        // k-group 0..3
  const int rhw = w * 8 + rh;   // node id matched by indicator row rh

  // ---- stage both message halves (straight copy of pre-packed dwords) ----
  for (int i = tid; i < 8192; i += 512) {
    int hb = i >> 12, n = (i >> 6) & 63, j = i & 63;
    ypk[hb * 4160 + n * 65 + j] = yp[(size_t)(g * 64 + n) * 128 + hb * 64 + j];
  }

  // ---- B fragments (We, fp16), both halves ----
  uint2 bfr[2][8];
#pragma unroll
  for (int hb = 0; hb < 2; ++hb)
#pragma unroll
    for (int c = 0; c < 8; ++c) {
      int d = hb * 128 + c * 16 + rh;
      bfr[hb][c].x = wep[(2 * qh) * 256 + d];
      bfr[hb][c].y = wep[(2 * qh + 1) * 256 + d];
    }

  __syncthreads();

  const int estart = st[g * 65 + w * 8];
  const int eend   = st[g * 65 + w * 8 + 8];

  f32x4 acc[2][8];
#pragma unroll
  for (int hb = 0; hb < 2; ++hb)
#pragma unroll
    for (int i = 0; i < 8; ++i) acc[hb][i] = (f32x4){0.f, 0.f, 0.f, 0.f};

  // ---- prefetch round 0 (mv masked to -1 for padding lanes) ----
  int base = estart;
  uint2 af = {0u, 0u};
  int mv = -1;
  if (base < eend) {
    int lim = eend - base; if (lim > 16) lim = 16;
    af = *(const uint2*)(eas + ((size_t)g * 2048 + base + (rh < lim ? rh : lim - 1)) * 8 + 2 * qh);
    int m = meta[(size_t)g * 2048 + base + (l < lim ? l : lim - 1)];
    mv = (l < lim) ? m : -1;
  }

  while (base < eend) {
    // ---- pull the 4 metas this lane needs (edges 4qh..4qh+3) — ONCE ----
    int mp[4];
#pragma unroll
    for (int v = 0; v < 4; ++v)
      mp[v] = __builtin_amdgcn_ds_bpermute(qh * 16 + v * 4, mv);

    // ---- prefetch next round — ONCE ----
    int nbase = base + 16;
    uint2 afn = af;
    int mvn = -1;
    if (nbase < eend) {
      int nlim = eend - nbase; if (nlim > 16) nlim = 16;
      afn = *(const uint2*)(eas + ((size_t)g * 2048 + nbase + (rh < nlim ? rh : nlim - 1)) * 8 + 2 * qh);
      int m2 = meta[(size_t)g * 2048 + nbase + (l < nlim ? l : nlim - 1)];
      mvn = (l < nlim) ? m2 : -1;
    }

    // ---- indicator fragment + src indices — ONCE ----
    int sv[4];
    unsigned int ind[4];
#pragma unroll
    for (int v = 0; v < 4; ++v) {
      sv[v] = mp[v] & 63;
      int dv = (mp[v] >> 8) & 255;          // padding -> 255, never matches
      ind[v] = (dv == rhw) ? 0x3C00u : 0u;  // f16 1.0 : 0.0
    }
    uint2 su;
    su.x = ind[0] | (ind[1] << 16);
    su.y = ind[2] | (ind[3] << 16);
    half4_t sfrag = __builtin_bit_cast(half4_t, su);
    half4_t afh = __builtin_bit_cast(half4_t, af);

    // ---- per half: MFMA#1, gather, msg build, MFMA#2 ----
    const h2v hz = {(_Float16)0.0f, (_Float16)0.0f};
#pragma unroll
    for (int hb = 0; hb < 2; ++hb) {
      f32x4 pa[4], pb[4];
#pragma unroll
      for (int cp = 0; cp < 4; ++cp) {
        f32x4 z = (f32x4){0.f, 0.f, 0.f, 0.f};
        pa[cp] = MFMA16F16(afh, __builtin_bit_cast(half4_t, bfr[hb][cp]), z, 0, 0, 0);
        pb[cp] = MFMA16F16(afh, __builtin_bit_cast(half4_t, bfr[hb][cp + 4]), z, 0, 0, 0);
      }

      unsigned int yv[4][4];
#pragma unroll
      for (int v = 0; v < 4; ++v) {
        const unsigned int* yb = ypk + hb * 4160 + sv[v] * 65 + rh;
        yv[0][v] = yb[0];
        yv[1][v] = yb[16];
        yv[2][v] = yb[32];
        yv[3][v] = yb[48];
      }

#pragma unroll
      for (int cp = 0; cp < 4; ++cp) {
        unsigned int t[4];
#pragma unroll
        for (int v = 0; v < 4; ++v) {
          h2v s = __builtin_bit_cast(h2v, pack_h2_fast(pa[cp][v], pb[cp][v]));
          s = s + __builtin_bit_cast(h2v, yv[cp][v]);      // v_pk_add_f16
          s = __builtin_elementwise_max(s, hz);            // v_pk_max_f16
          t[v] = __builtin_bit_cast(unsigned int, s);
        }
        uint2 blo, bhi;
        blo.x = __builtin_amdgcn_perm(t[1], t[0], 0x05040100u);
        blo.y = __builtin_amdgcn_perm(t[3], t[2], 0x05040100u);
        bhi.x = __builtin_amdgcn_perm(t[1], t[0], 0x07060302u);
        bhi.y = __builtin_amdgcn_perm(t[3], t[2], 0x07060302u);
        acc[hb][cp]     = MFMA16F16(sfrag, __builtin_bit_cast(half4_t, blo), acc[hb][cp], 0, 0, 0);
        acc[hb][cp + 4] = MFMA16F16(sfrag, __builtin_bit_cast(half4_t, bhi), acc[hb][cp + 4], 0, 0, 0);
      }
    }

    base = nbase;
    af = afn;
    mv = mvn;
  }

  // ---- epilogue: D2 rows 0..7 live in lanes qh<2 (row=4qh+v, col=rh) ----
  if (qh < 2) {
#pragma unroll
    for (int v = 0; v < 4; ++v) {
      int node = g * 64 + w * 8 + qh * 4 + v;
      const float* ysp = y2 + (size_t)node * 256 + rh;
      float* xop = xo + (size_t)node * 256 + rh;
      unsigned short* xohp = xoh + (size_t)node * 256 + rh;
#pragma unroll
      for (int hb = 0; hb < 2; ++hb)
#pragma unroll
        for (int cp = 0; cp < 8; ++cp) {
          int dim = hb * 128 + (cp & 3) * 16 + (cp >> 2) * 64;
          float val = fmaxf(ysp[dim] + acc[hb][cp][v], 0.f);
          if (WR32) xop[dim] = val;
          xohp[dim] = f2bf(val);
        }
    }
  }
}

__global__ __launch_bounds__(512, 4) void edge_conv_dual_wf(
    const unsigned int* __restrict__ ypA, const float* __restrict__ y2A,
    const int* __restrict__ meta1,
    const unsigned int* __restrict__ eas1, const unsigned int* __restrict__ wep1,
    const int* __restrict__ st1, float* __restrict__ xo1,
    unsigned short* __restrict__ xoh1,
    const unsigned int* __restrict__ ypB, const float* __restrict__ y2B,
    const int* __restrict__ meta2,
    const unsigned int* __restrict__ eas2, const unsigned int* __restrict__ wep2,
    const int* __restrict__ st2, float* __restrict__ xo2,
    unsigned short* __restrict__ xoh2)
{
  edge_conv_body<true>(ypA, y2A, meta1, eas1, wep1, st1, xo1, xoh1,
                       ypB, y2B, meta2, eas2, wep2, st2, xo2, xoh2);
}

__global__ __launch_bounds__(512, 4) void edge_conv_dual_nf(
    const unsigned int* __restrict__ ypA, const float* __restrict__ y2A,
    const int* __restrict__ meta1,
    const unsigned int* __restrict__ eas1, const unsigned int* __restrict__ wep1,
    const int* __restrict__ st1, float* __restrict__ xo1,
    unsigned short* __restrict__ xoh1,
    const unsigned int* __restrict__ ypB, const float* __restrict__ y2B,
    const int* __restrict__ meta2,
    const unsigned int* __restrict__ eas2, const unsigned int* __restrict__ wep2,
    const int* __restrict__ st2, float* __restrict__ xo2,
    unsigned short* __restrict__ xoh2)
{
  edge_conv_body<false>(ypA, y2A, meta1, eas1, wep1, st1, xo1, xoh1,
                        ypB, y2B, meta2, eas2, wep2, st2, xo2, xoh2);
}

// ---------------------------------------------------------------------------
// dot_pool v2: per graph, item = X1 @ X2^T [64x64] on the matrix pipe from
// the bf16 twins. One block/graph; 64KB LDS, chunk-XOR swizzle (2-way = free).
// ---------------------------------------------------------------------------
__global__ __launch_bounds__(256) void dot_pool_mfma(
    const unsigned short* __restrict__ x1h, const unsigned short* __restrict__ x2h,
    float* __restrict__ fusion, int step)
{
  __shared__ unsigned short s1[64][256];
  __shared__ unsigned short s2[64][256];
  const int g = blockIdx.x, tid = threadIdx.x;
  const int l = tid & 63, w = tid >> 6;
  const int r = l & 15, q = l >> 4;

  for (int i = tid; i < 2048; i += 256) {
    int row = i >> 5, c = i & 31;
    int cs = c ^ (row & 7);
    *(uint4*)&s1[row][cs * 8] = *(const uint4*)(x1h + (size_t)(g * 64 + row) * 256 + c * 8);
    *(uint4*)&s2[row][cs * 8] = *(const uint4*)(x2h + (size_t)(g * 64 + row) * 256 + c * 8);
  }
  __syncthreads();

  const int m0 = w * 16;
  const int sx = r & 7;
  f32x4 acc[4];
#pragma unroll
  for (int nt = 0; nt < 4; ++nt) acc[nt] = (f32x4){0.f, 0.f, 0.f, 0.f};

#pragma unroll
  for (int kb = 0; kb < 32; kb += 4) {     // 8 K-chunks of 32 (4 x 8-ushort)
    int ch = (kb + q) ^ sx;
    short8_t af = *(const short8_t*)&s1[m0 + r][ch * 8];
#pragma unroll
    for (int nt = 0; nt < 4; ++nt) {
      short8_t bf = *(const short8_t*)&s2[nt * 16 + r][ch * 8];
      acc[nt] = __builtin_amdgcn_mfma_f32_16x16x32_bf16(af, bf, acc[nt], 0, 0, 0);
    }
  }

  float mymax = -1e30f, mysum = 0.f;
#pragma unroll
  for (int nt = 0; nt < 4; ++nt)
#pragma unroll
    for (int reg = 0; reg < 4; ++reg) {
      float v = acc[nt][reg];
      mymax = fmaxf(mymax, v);
      mysum += v;
    }
  for (int off = 32; off; off >>= 1) {
    mymax = fmaxf(mymax, __shfl_down(mymax, off, 64));
    mysum += __shfl_down(mysum, off, 64);
  }
  __syncthreads();                       // LDS reads done; reuse s1 as scratch
  float* red = (float*)&s1[0][0];
  if (l == 0) { red[w] = mymax; red[8 + w] = mysum; }
  __syncthreads();
  if (tid == 0) {
    float gm = fmaxf(fmaxf(red[0], red[1]), fmaxf(red[2], red[3]));
    float gs = red[8] + red[9] + red[10] + red[11];
    fusion[g * 6 + step * 2] = gm;
    fusion[g * 6 + step * 2 + 1] = gs * (1.f / 4096.f);
  }
}

// ---------------------------------------------------------------------------
// readout (dual, grid 512): R[g] = [mean | sum | top3-by-last-col rows]
// ---------------------------------------------------------------------------
__global__ __launch_bounds__(256) void readout_dual(
    const float* __restrict__ xm1, const float* __restrict__ xm2,
    float* __restrict__ R1, float* __restrict__ R2)
{
  const int mol = blockIdx.x >> 8;
  const float* xm = mol ? xm2 : xm1;
  float* R = mol ? R2 : R1;
  __shared__ float lastcol[64];
  __shared__ int topi[3];
  const int g = blockIdx.x & 255, d = threadIdx.x;
  float s = 0.f;
  for (int n = 0; n < 64; ++n) s += xm[(size_t)(g * 64 + n) * 256 + d];
  R[(size_t)g * 1280 + d] = s * (1.f / 64.f);
  R[(size_t)g * 1280 + 256 + d] = s;
  if (d < 64) lastcol[d] = xm[(size_t)(g * 64 + d) * 256 + 255];
  __syncthreads();
  if (d == 0) {
    unsigned long long used = 0;
    for (int j = 0; j < 3; ++j) {
      float best = -1e30f;
      int bi = 0;
      for (int n = 0; n < 64; ++n) {
        if ((used >> n) & 1ull) continue;
        if (lastcol[n] > best) { best = lastcol[n]; bi = n; }
      }
      used |= (1ull << bi);
      topi[j] = bi;
    }
  }
  __syncthreads();
  for (int j = 0; j < 3; ++j)
    R[(size_t)g * 1280 + 512 + j * 256 + d] =
        xm[(size_t)(g * 64 + topi[j]) * 256 + d];
}

// ---------------------------------------------------------------------------
// final head: cat = [sum_k P1[k] + bf1 | sum_k P2[k] + bf2 | fusion];
// out = (cat @ Wo1 + bo1) @ Wo2 + bo2
// ---------------------------------------------------------------------------
__global__ __launch_bounds__(256) void final_head(
    const float* __restrict__ P1, const float* __restrict__ P2,
    const float* __restrict__ bf1, const float* __restrict__ bf2,
    const float* __restrict__ fusion,
    const float* __restrict__ Wo1, const float* __restrict__ bo1,
    const float* __restrict__ Wo2, const float* __restrict__ bo2,
    float* __restrict__ out)
{
  __shared__ float cat[520];
  __shared__ float r0s[4], r1s[4];
  const int g = blockIdx.x, t = threadIdx.x;
  float s1 = bf1[t], s2 = bf2[t];
#pragma unroll
  for (int k = 0; k < NKSPLIT; ++k) {
    s1 += P1[((size_t)k * 256 + g) * 256 + t];
    s2 += P2[((size_t)k * 256 + g) * 256 + t];
  }
  cat[t] = s1;
  cat[256 + t] = s2;
  if (t < 6) cat[512 + t] = fusion[g * 6 + t];
  __syncthreads();
  float a0 = 0.f, a1 = 0.f, a2 = 0.f, a3 = 0.f;
  for (int k = 0; k < 516; k += 4) {
    a0 = fmaf(cat[k],     Wo1[(size_t)(k)     * 256 + t], a0);
    a1 = fmaf(cat[k + 1], Wo1[(size_t)(k + 1) * 256 + t], a1);
    a2 = fmaf(cat[k + 2], Wo1[(size_t)(k + 2) * 256 + t], a2);
    a3 = fmaf(cat[k + 3], Wo1[(size_t)(k + 3) * 256 + t], a3);
  }
  a0 = fmaf(cat[516], Wo1[(size_t)516 * 256 + t], a0);
  a1 = fmaf(cat[517], Wo1[(size_t)517 * 256 + t], a1);
  float acc = bo1[t] + ((a0 + a1) + (a2 + a3));
  float p0 = acc * Wo2[t * 2];
  float p1 = acc * Wo2[t * 2 + 1];
  for (int off = 32; off; off >>= 1) {
    p0 += __shfl_down(p0, off, 64);
    p1 += __shfl_down(p1, off, 64);
  }
  if ((t & 63) == 0) { r0s[t >> 6] = p0; r1s[t >> 6] = p1; }
  __syncthreads();
  if (t == 0) {
    out[g * 2] = r0s[0] + r0s[1] + r0s[2] + r0s[3] + bo2[0];
    out[g * 2 + 1] = r1s[0] + r1s[1] + r1s[2] + r1s[3] + bo2[1];
  }
}

// ---------------------------------------------------------------------------
// Weight transposes, recoalesced: LDS tile per 64-k-row slab, coalesced
// fp32 reads and uint4 bf16 writes. Grid 60.
// ---------------------------------------------------------------------------
__global__ __launch_bounds__(256) void transpose_all(
    const float* __restrict__ W0_1, const float* __restrict__ W0_2,
    const float* __restrict__ Wn1, const float* __restrict__ Ws1,
    const float* __restrict__ Wn2, const float* __restrict__ Ws2,
    const float* __restrict__ Wf1, const float* __restrict__ Wf2,
    unsigned short* __restrict__ W0T1, unsigned short* __restrict__ W0T2,
    unsigned short* __restrict__ WcT1, unsigned short* __restrict__ WcT2,
    unsigned short* __restrict__ WfT1, unsigned short* __restrict__ WfT2)
{
  const int b = blockIdx.x;
  const float* src; unsigned short* dst; int k0, K;
  if (b < 2)       { src = W0_1; dst = W0T1;         K = 128;  k0 = b * 64; }
  else if (b < 4)  { src = W0_2; dst = W0T2;         K = 128;  k0 = (b - 2) * 64; }
  else if (b < 8)  { src = Wn1;  dst = WcT1;         K = 256;  k0 = (b - 4) * 64; }
  else if (b < 12) { src = Ws1;  dst = WcT1 + 65536; K = 256;  k0 = (b - 8) * 64; }
  else if (b < 16) { src = Wn2;  dst = WcT2;         K = 256;  k0 = (b - 12) * 64; }
  else if (b < 20) { src = Ws2;  dst = WcT2 + 65536; K = 256;  k0 = (b - 16) * 64; }
  else if (b < 40) { src = Wf1;  dst = WfT1;         K = 1280; k0 = (b - 20) * 64; }
  else             { src = Wf2;  dst = WfT2;         K = 1280; k0 = (b - 40) * 64; }

  __shared__ unsigned short t[64][258];
  const int tid = threadIdx.x;
  for (int i = tid; i < 16384; i += 256) {
    int row = i >> 8, col = i & 255;
    t[row][col] = f2bf(src[(size_t)(k0 + row) * 256 + col]);
  }
  __syncthreads();
  unsigned short* dp = dst + (size_t)tid * K + k0;
  for (int k = 0; k < 64; k += 8) {
    uint4 v;
    v.x = (unsigned)t[k + 0][tid] | ((unsigned)t[k + 1][tid] << 16);
    v.y = (unsigned)t[k + 2][tid] | ((unsigned)t[k + 3][tid] << 16);
    v.z = (unsigned)t[k + 4][tid] | ((unsigned)t[k + 5][tid] << 16);
    v.w = (unsigned)t[k + 6][tid] | ((unsigned)t[k + 7][tid] << 16);
    *(uint4*)(dp + k) = v;
  }
}

__global__ void misc_prep(
    const float* bm1, const float* bs1, const float* bm2, const float* bs2,
    const float* We1, const float* We2,
    float* bcat1, float* bcat2,
    unsigned int* weh1, unsigned int* weh2)
{
  int idx = blockIdx.x * 256 + threadIdx.x;  // grid 20 -> 5120
  if (idx < 512) {
    bcat1[idx] = idx < 256 ? bm1[idx] : bs1[idx - 256];
  } else if (idx < 1024) {
    int i = idx - 512;
    bcat2[i] = i < 256 ? bm2[i] : bs2[i - 256];
  } else if (idx < 3072) {
    int i = idx - 1024, j = i >> 8, d = i & 255;
    weh1[i] = pack_h2(We1[(2 * j) * 256 + d], We1[(2 * j + 1) * 256 + d]);
  } else if (idx < 5120) {
    int i = idx - 3072, j = i >> 8, d = i & 255;
    weh2[i] = pack_h2(We2[(2 * j) * 256 + d], We2[(2 * j + 1) * 256 + d]);
  }
}

// ---------------------------------------------------------------------------
extern "C" void kernel_launch(void* const* d_in, const int* in_sizes, int n_in,
                              void* d_out, int out_size, void* d_ws, size_t ws_size,
                              hipStream_t stream)
{
  const float* x1 = (const float*)d_in[0];
  const int* ei1 = (const int*)d_in[1];
  const float* ea1 = (const float*)d_in[2];
  const float* x2 = (const float*)d_in[4];
  const int* ei2 = (const int*)d_in[5];
  const float* ea2 = (const float*)d_in[6];
  const float* W0_1 = (const float*)d_in[8];
  const float* b0_1 = (const float*)d_in[9];
  const float* W0_2 = (const float*)d_in[10];
  const float* b0_2 = (const float*)d_in[11];
  const float* Wn1 = (const float*)d_in[12];
  const float* We1 = (const float*)d_in[13];
  const float* bm1 = (const float*)d_in[14];
  const float* Ws1 = (const float*)d_in[15];
  const float* bs1 = (const float*)d_in[16];
  const float* Wn2 = (const float*)d_in[17];
  const float* We2 = (const float*)d_in[18];
  const float* bm2 = (const float*)d_in[19];
  const float* Ws2 = (const float*)d_in[20];
  const float* bs2 = (const float*)d_in[21];
  const float* Wf1 = (const float*)d_in[22];
  const float* bf1 = (const float*)d_in[23];
  const float* Wf2 = (const float*)d_in[24];
  const float* bf2 = (const float*)d_in[25];
  const float* Wo1 = (const float*)d_in[26];
  const float* bo1 = (const float*)d_in[27];
  const float* Wo2 = (const float*)d_in[28];
  const float* bo2 = (const float*)d_in[29];
  float* out = (float*)d_out;

  float* w = (float*)d_ws;
  size_t off = 0;
  auto alloc = [&](size_t nf) { float* p = w + off; off += nf; return p; };
  float* xmA1 = alloc(4194304);
  float* xmA2 = alloc(4194304);
  float* xmB1 = alloc(4194304);
  float* xmB2 = alloc(4194304);
  unsigned int* yp1 = (unsigned int*)alloc(2097152);
  unsigned int* yp2 = (unsigned int*)alloc(2097152);
  float* y2a1 = alloc(4194304);
  float* y2a2 = alloc(4194304);
  float* R1 = alloc(327680);
  float* R2 = alloc(327680);
  float* P1 = alloc(655360);
  float* P2 = alloc(655360);
  float* fusion = alloc(1536);
  float* bcat1 = alloc(512);
  float* bcat2 = alloc(512);
  unsigned short* W0T1 = (unsigned short*)alloc(16384);
  unsigned short* W0T2 = (unsigned short*)alloc(16384);
  unsigned short* WcT1 = (unsigned short*)alloc(65536);
  unsigned short* WcT2 = (unsigned short*)alloc(65536);
  unsigned short* WfT1 = (unsigned short*)alloc(163840);
  unsigned short* WfT2 = (unsigned short*)alloc(163840);
  unsigned int* weh1 = (unsigned int*)alloc(2048);
  unsigned int* weh2 = (unsigned int*)alloc(2048);
  unsigned int* eah1 = (unsigned int*)alloc(4194304);
  unsigned int* eah2 = (unsigned int*)alloc(4194304);
  int* meta1 = (int*)alloc(524288);
  int* meta2 = (int*)alloc(524288);
  int* perm1 = (int*)alloc(524288);
  int* perm2 = (int*)alloc(524288);
  int* starts1 = (int*)alloc(16640);
  int* starts2 = (int*)alloc(16640);
  unsigned short* xmhA1 = (unsigned short*)alloc(2097152);
  unsigned short* xmhA2 = (unsigned short*)alloc(2097152);
  unsigned short* xmhB1 = (unsigned short*)alloc(2097152);
  unsigned short* xmhB2 = (unsigned short*)alloc(2097152);
  (void)in_sizes; (void)n_in; (void)out_size; (void)ws_size;

  // ---- prep ----
  sort_edges_dual<<<512, 256, 0, stream>>>(ei1, ei2, meta1, meta2,
                                           perm1, perm2, starts1, starts2);
  transpose_all<<<60, 256, 0, stream>>>(W0_1, W0_2, Wn1, Ws1, Wn2, Ws2,
                                        Wf1, Wf2, W0T1, W0T2, WcT1, WcT2,
                                        WfT1, WfT2);
  misc_prep<<<20, 256, 0, stream>>>(bm1, bs1, bm2, bs2, We1, We2,
                                    bcat1, bcat2, weh1, weh2);
  ea_gather_pack_dual<<<4096, 256, 0, stream>>>(ea1, ea2, perm1, perm2,
                                                eah1, eah2);

  // ---- embed: xmh = bf16(rrelu(x @ W0 + b0)) ----
  gemm_bf16_dual<<<dim3(128, 2, 2), 256, 0, stream>>>(
      x1, W0T1, b0_1, nullptr, xmhA1, x2, W0T2, b0_2, nullptr, xmhA2,
      128, 256, 128, 2);

  // ---- 3 message-passing steps ----
  float* cur1 = xmA1; float* cur2 = xmA2;
  float* nxt1 = xmB1; float* nxt2 = xmB2;
  unsigned short* curh1 = xmhA1; unsigned short* curh2 = xmhA2;
  unsigned short* nxth1 = xmhB1; unsigned short* nxth2 = xmhB2;
  for (int step = 0; step < 3; ++step) {
    gemm_h_dual<<<dim3(128, 4, 2), 256, 0, stream>>>(
        curh1, WcT1, bcat1, yp1, y2a1, curh2, WcT2, bcat2, yp2, y2a2, 256);
    if (step == 2) {
      edge_conv_dual_wf<<<dim3(256, 1, 2), 512, 0, stream>>>(
          yp1, y2a1, meta1, eah1, weh1, starts1, nxt1, nxth1,
          yp2, y2a2, meta2, eah2, weh2, starts2, nxt2, nxth2);
    } else {
      edge_conv_dual_nf<<<dim3(256, 1, 2), 512, 0, stream>>>(
          yp1, y2a1, meta1, eah1, weh1, starts1, nxt1, nxth1,
          yp2, y2a2, meta2, eah2, weh2, starts2, nxt2, nxth2);
    }
    dot_pool_mfma<<<256, 256, 0, stream>>>(nxth1, nxth2, fusion, step);
    float* t1 = cur1; cur1 = nxt1; nxt1 = t1;
    float* t2 = cur2; cur2 = nxt2; nxt2 = t2;
    unsigned short* th1 = curh1; curh1 = nxth1; nxth1 = th1;
    unsigned short* th2 = curh2; curh2 = nxth2; nxth2 = th2;
  }

  // ---- readout + split-K head GEMM + final head ----
  readout_dual<<<512, 256, 0, stream>>>(cur1, cur2, R1, R2);
  gemm_splitk_dual<<<dim3(4, 4, 2 * NKSPLIT), 256, 0, stream>>>(
      R1, WfT1, P1, R2, WfT2, P2);
  final_head<<<256, 256, 0, stream>>>(P1, P2, bf1, bf2, fusion,
                                      Wo1, bo1, Wo2, bo2, out);
}

// Round 15
// 475.755 us; speedup vs baseline: 1.1285x; 1.1285x over previous
//
#include <hip/hip_runtime.h>
#include <hip/hip_fp16.h>

// Problem constants (fixed by setup_inputs)
#define E_TOTAL 524288
#define RRELU_SLOPE 0.22916666666666666f
#define NKSPLIT 10

typedef float f32x4 __attribute__((ext_vector_type(4)));
typedef short short8_t __attribute__((ext_vector_type(8)));
typedef _Float16 half4_t __attribute__((ext_vector_type(4)));
typedef _Float16 h2v __attribute__((ext_vector_type(2)));

// Direct builtin call (host pass defers diagnostics for target builtins
// inside __global__ bodies — round-3 lesson: no host-side stubs/guards).
#define MFMA16F16 __builtin_amdgcn_mfma_f32_16x16x16f16

#if defined(__HIP_DEVICE_COMPILE__)
# if __has_builtin(__builtin_amdgcn_cvt_pkrtz)
#  define HAVE_PKRTZ 1
# endif
#endif

__device__ inline unsigned short f2bf(float x) {
  unsigned int u = __float_as_uint(x);
  u += 0x7FFFu + ((u >> 16) & 1u);   // RNE
  return (unsigned short)(u >> 16);
}

__device__ inline unsigned int pack_h2(float a, float b) {
  __half2 h = __floats2half2_rn(a, b);
  return __builtin_bit_cast(unsigned int, h);
}

__device__ inline unsigned int pack_h2_fast(float a, float b) {
#ifdef HAVE_PKRTZ
  return __builtin_bit_cast(unsigned int, __builtin_amdgcn_cvt_pkrtz(a, b));
#else
  return pack_h2(a, b);
#endif
}

// ---------------------------------------------------------------------------
// Generic bf16-MFMA GEMM (fp32 A), dual parameter set via blockIdx.z.
// C[M,N] = act(A @ B + bias). If Ch != null, write bf16 output instead of C.
// Grid: (M/128, N/128, 2). act: 0=none, 2=rrelu
// ---------------------------------------------------------------------------
__global__ __launch_bounds__(256) void gemm_bf16_dual(
    const float* __restrict__ A1, const unsigned short* __restrict__ BT1,
    const float* __restrict__ bias1, float* __restrict__ C1,
    unsigned short* __restrict__ Ch1,
    const float* __restrict__ A2, const unsigned short* __restrict__ BT2,
    const float* __restrict__ bias2, float* __restrict__ C2,
    unsigned short* __restrict__ Ch2,
    int lda, int ldc, int K, int act)
{
  const float* A = blockIdx.z ? A2 : A1;
  const unsigned short* BT = blockIdx.z ? BT2 : BT1;
  const float* bias = blockIdx.z ? bias2 : bias1;
  float* C = blockIdx.z ? C2 : C1;
  unsigned short* Ch = blockIdx.z ? Ch2 : Ch1;

  __shared__ unsigned short As[128][32];
  __shared__ unsigned short Bs[128][32];
  const int tid = threadIdx.x;
  const int bm = blockIdx.x, bn = blockIdx.y;
  const int w = tid >> 6, l = tid & 63;
  const int wm = (w & 1) * 64, wn = (w >> 1) * 64;
  const int q = l >> 4, r = l & 15;

  f32x4 acc[4][4];
  for (int i = 0; i < 4; ++i)
    for (int j = 0; j < 4; ++j)
      acc[i][j] = (f32x4){0.f, 0.f, 0.f, 0.f};

  const int sm = tid >> 1;
  const int sk = (tid & 1) * 16;
  const float* ap = A + (size_t)(bm * 128 + sm) * lda + sk;
  const unsigned short* bp = BT + (size_t)(bn * 128 + sm) * K + sk;

  for (int k0 = 0; k0 < K; k0 += 32) {
    float4 f0 = *(const float4*)(ap + k0);
    float4 f1 = *(const float4*)(ap + k0 + 4);
    float4 f2 = *(const float4*)(ap + k0 + 8);
    float4 f3 = *(const float4*)(ap + k0 + 12);
    uint4 p0, p1;
    p0.x = (unsigned)f2bf(f0.x) | ((unsigned)f2bf(f0.y) << 16);
    p0.y = (unsigned)f2bf(f0.z) | ((unsigned)f2bf(f0.w) << 16);
    p0.z = (unsigned)f2bf(f1.x) | ((unsigned)f2bf(f1.y) << 16);
    p0.w = (unsigned)f2bf(f1.z) | ((unsigned)f2bf(f1.w) << 16);
    p1.x = (unsigned)f2bf(f2.x) | ((unsigned)f2bf(f2.y) << 16);
    p1.y = (unsigned)f2bf(f2.z) | ((unsigned)f2bf(f2.w) << 16);
    p1.z = (unsigned)f2bf(f3.x) | ((unsigned)f2bf(f3.y) << 16);
    p1.w = (unsigned)f2bf(f3.z) | ((unsigned)f2bf(f3.w) << 16);
    *(uint4*)&As[sm][sk] = p0;
    *(uint4*)&As[sm][sk + 8] = p1;
    uint4 b0 = *(const uint4*)(bp + k0);
    uint4 b1 = *(const uint4*)(bp + k0 + 8);
    *(uint4*)&Bs[sm][sk] = b0;
    *(uint4*)&Bs[sm][sk + 8] = b1;
    __syncthreads();

    short8_t af[4], bfr[4];
    for (int mt = 0; mt < 4; ++mt)
      af[mt] = *(const short8_t*)&As[wm + mt * 16 + r][q * 8];
    for (int nt = 0; nt < 4; ++nt)
      bfr[nt] = *(const short8_t*)&Bs[wn + nt * 16 + r][q * 8];
    for (int mt = 0; mt < 4; ++mt)
      for (int nt = 0; nt < 4; ++nt)
        acc[mt][nt] = __builtin_amdgcn_mfma_f32_16x16x32_bf16(
            af[mt], bfr[nt], acc[mt][nt], 0, 0, 0);
    __syncthreads();
  }

  for (int nt = 0; nt < 4; ++nt) {
    int gc = bn * 128 + wn + nt * 16 + r;
    float bv = bias ? bias[gc] : 0.f;
    for (int mt = 0; mt < 4; ++mt) {
      int gm = bm * 128 + wm + mt * 16 + q * 4;
      for (int rr = 0; rr < 4; ++rr) {
        float v = acc[mt][nt][rr] + bv;
        if (act == 2) v = (v >= 0.f) ? v : v * RRELU_SLOPE;
        if (Ch) Ch[(size_t)(gm + rr) * ldc + gc] = f2bf(v);
        else    C[(size_t)(gm + rr) * ldc + gc] = v;
      }
    }
  }
}

// ---------------------------------------------------------------------------
// y-GEMM (bf16 A): y[M,512] = A @ Wcat + bcat, dual via blockIdx.z.
// Grid (128,4,2). Output split:
//  bn 0,1 (cols 0..255, message half): packed fp16 pair-dwords
//    yp[row*128 + bn*64 + j] = h2(y[bn*128+j], y[bn*128+j+64]), j in [0,64).
//  bn 2,3 (cols 256..511, self half): fp32 to y2[row*256 + col].
// Staging via global_load_lds width=16.
// ---------------------------------------------------------------------------
__global__ __launch_bounds__(256) void gemm_h_dual(
    const unsigned short* __restrict__ Ah1, const unsigned short* __restrict__ BT1,
    const float* __restrict__ bias1, unsigned int* __restrict__ yp1,
    float* __restrict__ y2o1,
    const unsigned short* __restrict__ Ah2, const unsigned short* __restrict__ BT2,
    const float* __restrict__ bias2, unsigned int* __restrict__ yp2,
    float* __restrict__ y2o2,
    int K)
{
  const unsigned short* A = blockIdx.z ? Ah2 : Ah1;
  const unsigned short* BT = blockIdx.z ? BT2 : BT1;
  const float* bias = blockIdx.z ? bias2 : bias1;
  unsigned int* yp = blockIdx.z ? yp2 : yp1;
  float* y2o = blockIdx.z ? y2o2 : y2o1;

  __shared__ unsigned short As[128][32];
  __shared__ unsigned short Bs[128][32];
  const int tid = threadIdx.x;
  const int bm = blockIdx.x, bn = blockIdx.y;
  const int w = tid >> 6, l = tid & 63;
  const int wm = (w & 1) * 64;
  const int q = l >> 4, r = l & 15;
  const bool packed = bn < 2;
  const int wn2 = (w >> 1) * 32;     // packed-mode col base
  const int wn = (w >> 1) * 64;      // plain-mode col base

  // col-within-block of tile nt for this wave
  int colb[4];
#pragma unroll
  for (int nt = 0; nt < 4; ++nt)
    colb[nt] = packed ? (wn2 + (nt & 1) * 16 + (nt >> 1) * 64) : (wn + nt * 16);

  f32x4 acc[4][4];
  for (int i = 0; i < 4; ++i)
    for (int j = 0; j < 4; ++j)
      acc[i][j] = (f32x4){0.f, 0.f, 0.f, 0.f};

  const int gr = l >> 2;          // row within 16-row chunk
  const int gk = (l & 3) * 8;     // short offset within K-tile of 32
  const unsigned short* aw = A + (size_t)(bm * 128 + w * 32 + gr) * K + gk;
  const unsigned short* bw = BT + (size_t)(bn * 128 + w * 32 + gr) * K + gk;

  for (int k0 = 0; k0 < K; k0 += 32) {
    __builtin_amdgcn_global_load_lds(
        (const __attribute__((address_space(1))) unsigned int*)(aw + k0),
        (__attribute__((address_space(3))) unsigned int*)&As[w * 32][0], 16, 0, 0);
    __builtin_amdgcn_global_load_lds(
        (const __attribute__((address_space(1))) unsigned int*)(aw + (size_t)16 * K + k0),
        (__attribute__((address_space(3))) unsigned int*)&As[w * 32 + 16][0], 16, 0, 0);
    __builtin_amdgcn_global_load_lds(
        (const __attribute__((address_space(1))) unsigned int*)(bw + k0),
        (__attribute__((address_space(3))) unsigned int*)&Bs[w * 32][0], 16, 0, 0);
    __builtin_amdgcn_global_load_lds(
        (const __attribute__((address_space(1))) unsigned int*)(bw + (size_t)16 * K + k0),
        (__attribute__((address_space(3))) unsigned int*)&Bs[w * 32 + 16][0], 16, 0, 0);
    __syncthreads();

    short8_t af[4], bfr[4];
    for (int mt = 0; mt < 4; ++mt)
      af[mt] = *(const short8_t*)&As[wm + mt * 16 + r][q * 8];
    for (int nt = 0; nt < 4; ++nt)
      bfr[nt] = *(const short8_t*)&Bs[colb[nt] + r][q * 8];
    for (int mt = 0; mt < 4; ++mt)
      for (int nt = 0; nt < 4; ++nt)
        acc[mt][nt] = __builtin_amdgcn_mfma_f32_16x16x32_bf16(
            af[mt], bfr[nt], acc[mt][nt], 0, 0, 0);
    __syncthreads();
  }

  if (packed) {
    for (int nt2 = 0; nt2 < 2; ++nt2) {
      int j = wn2 + nt2 * 16 + r;              // dword idx in [0,64)
      float blo = bias[bn * 128 + j];
      float bhi = bias[bn * 128 + j + 64];
      for (int mt = 0; mt < 4; ++mt) {
        int gm = bm * 128 + wm + mt * 16 + q * 4;
        for (int rr = 0; rr < 4; ++rr) {
          float lo = acc[mt][nt2][rr] + blo;
          float hi = acc[mt][nt2 + 2][rr] + bhi;
          yp[(size_t)(gm + rr) * 128 + bn * 64 + j] = pack_h2_fast(lo, hi);
        }
      }
    }
  } else {
    for (int nt = 0; nt < 4; ++nt) {
      int col = (bn - 2) * 128 + wn + nt * 16 + r;   // in [0,256)
      float bv = bias[256 + col];
      for (int mt = 0; mt < 4; ++mt) {
        int gm = bm * 128 + wm + mt * 16 + q * 4;
        for (int rr = 0; rr < 4; ++rr)
          y2o[(size_t)(gm + rr) * 256 + col] = acc[mt][nt][rr] + bv;
      }
    }
  }
}

// ---------------------------------------------------------------------------
// Split-K readout GEMM: P[kc][M=256][N=256] += A[256][1280] @ BT[256][1280]^T
// per K-chunk of 128. Grid (4,4,2*NKSPLIT): z = mol | kc<<1.
// ---------------------------------------------------------------------------
__global__ __launch_bounds__(256) void gemm_splitk_dual(
    const float* __restrict__ A1, const unsigned short* __restrict__ BT1,
    float* __restrict__ P1,
    const float* __restrict__ A2, const unsigned short* __restrict__ BT2,
    float* __restrict__ P2)
{
  const int mol = blockIdx.z & 1;
  const int kc = blockIdx.z >> 1;
  const float* A = mol ? A2 : A1;
  const unsigned short* BT = mol ? BT2 : BT1;
  float* P = mol ? P2 : P1;
  const int K = 1280;

  __shared__ unsigned short As[64][32];
  __shared__ unsigned short Bs[64][32];
  const int tid = threadIdx.x;
  const int m0 = blockIdx.x * 64, n0 = blockIdx.y * 64;
  const int w = tid >> 6, l = tid & 63;
  const int wm = (w & 1) * 32, wn = (w >> 1) * 32;
  const int q = l >> 4, r = l & 15;

  f32x4 acc[2][2];
  for (int i = 0; i < 2; ++i)
    for (int j = 0; j < 2; ++j)
      acc[i][j] = (f32x4){0.f, 0.f, 0.f, 0.f};

  const int sm = tid >> 2;        // 0..63
  const int sk = (tid & 3) * 8;   // 0,8,16,24
  const float* ap = A + (size_t)(m0 + sm) * K + kc * 128 + sk;
  const unsigned short* bp = BT + (size_t)(n0 + sm) * K + kc * 128 + sk;

  for (int k0 = 0; k0 < 128; k0 += 32) {
    float4 f0 = *(const float4*)(ap + k0);
    float4 f1 = *(const float4*)(ap + k0 + 4);
    uint4 p0;
    p0.x = (unsigned)f2bf(f0.x) | ((unsigned)f2bf(f0.y) << 16);
    p0.y = (unsigned)f2bf(f0.z) | ((unsigned)f2bf(f0.w) << 16);
    p0.z = (unsigned)f2bf(f1.x) | ((unsigned)f2bf(f1.y) << 16);
    p0.w = (unsigned)f2bf(f1.z) | ((unsigned)f2bf(f1.w) << 16);
    *(uint4*)&As[sm][sk] = p0;
    *(uint4*)&Bs[sm][sk] = *(const uint4*)(bp + k0);
    __syncthreads();

    short8_t af[2], bfr[2];
    for (int mt = 0; mt < 2; ++mt)
      af[mt] = *(const short8_t*)&As[wm + mt * 16 + r][q * 8];
    for (int nt = 0; nt < 2; ++nt)
      bfr[nt] = *(const short8_t*)&Bs[wn + nt * 16 + r][q * 8];
    for (int mt = 0; mt < 2; ++mt)
      for (int nt = 0; nt < 2; ++nt)
        acc[mt][nt] = __builtin_amdgcn_mfma_f32_16x16x32_bf16(
            af[mt], bfr[nt], acc[mt][nt], 0, 0, 0);
    __syncthreads();
  }

  for (int nt = 0; nt < 2; ++nt) {
    int gc = n0 + wn + nt * 16 + r;
    for (int mt = 0; mt < 2; ++mt) {
      int gm = m0 + wm + mt * 16 + q * 4;
      for (int rr = 0; rr < 4; ++rr)
        P[((size_t)kc * 256 + gm + rr) * 256 + gc] = acc[mt][nt][rr];
    }
  }
}

// ---------------------------------------------------------------------------
// Per-graph counting sort of edges by destination node, FUSED with the ea
// gather+fp16 pack (v17): the placement loop knows each edge's sorted slot p,
// so pack ea straight to eah[p] — coalesced 64B reads by original index,
// scattered-but-L2-local writes. Deletes the separate 4096-block gather
// kernel and the perm arrays. Dual-mol grid 512.
// ---------------------------------------------------------------------------
__global__ __launch_bounds__(256) void sort_edges_dual(
    const int* __restrict__ ei1, const int* __restrict__ ei2,
    const float* __restrict__ ea1, const float* __restrict__ ea2,
    int* __restrict__ meta1, int* __restrict__ meta2,
    unsigned int* __restrict__ eah1, unsigned int* __restrict__ eah2,
    int* __restrict__ starts1, int* __restrict__ starts2)
{
  const int mol = blockIdx.x >> 8;
  const int g = blockIdx.x & 255;
  const int* eidx = mol ? ei2 : ei1;
  const float* ea = mol ? ea2 : ea1;
  int* meta = mol ? meta2 : meta1;
  unsigned int* eah = mol ? eah2 : eah1;
  int* starts = mol ? starts2 : starts1;

  __shared__ int cnt[4][64];
  __shared__ int startS[65];
  __shared__ int cur[64];
  const int t = threadIdx.x, w = t >> 6;
  cnt[w][t & 63] = 0;
  if (t < 64) cur[t] = 0;
  __syncthreads();
  for (int i = t; i < 2048; i += 256)
    atomicAdd(&cnt[w][eidx[E_TOTAL + g * 2048 + i] & 63], 1);
  __syncthreads();
  if (t == 0) {
    int acc = 0;
    for (int n = 0; n < 64; ++n) {
      startS[n] = acc;
      acc += cnt[0][n] + cnt[1][n] + cnt[2][n] + cnt[3][n];
    }
    startS[64] = acc;
  }
  __syncthreads();
  if (t < 65) starts[g * 65 + t] = startS[t];
  for (int i = t; i < 2048; i += 256) {
    int s = eidx[g * 2048 + i] & 63;
    int d = eidx[E_TOTAL + g * 2048 + i] & 63;
    int p = startS[d] + atomicAdd(&cur[d], 1);
    meta[g * 2048 + p] = s | (d << 8);
    const float* sp = ea + (size_t)(g * 2048 + i) * 16;
    float4 v0 = *(const float4*)(sp);
    float4 v1 = *(const float4*)(sp + 4);
    float4 v2 = *(const float4*)(sp + 8);
    float4 v3 = *(const float4*)(sp + 12);
    uint4 q0, q1;
    q0.x = pack_h2(v0.x, v0.y); q0.y = pack_h2(v0.z, v0.w);
    q0.z = pack_h2(v1.x, v1.y); q0.w = pack_h2(v1.z, v1.w);
    q1.x = pack_h2(v2.x, v2.y); q1.y = pack_h2(v2.z, v2.w);
    q1.z = pack_h2(v3.x, v3.y); q1.w = pack_h2(v3.z, v3.w);
    unsigned int* op = eah + (size_t)(g * 2048 + p) * 8;
    *(uint4*)op = q0;
    *(uint4*)(op + 4) = q1;
  }
}

// ---------------------------------------------------------------------------
// Edge conv (round-13 verified structure, grid (512,1,2), per-half blocks):
//  - ypk staging: straight dword copy from producer-packed yp
//  - self half from y2 (fp32)
//  - WR32 compile-time template (round 9-11 lesson: no runtime flags)
// Round-14's merged-halves variant regressed (latency-bound at half the
// block count) and is reverted.
// ---------------------------------------------------------------------------
template <bool WR32>
__device__ __forceinline__ void edge_conv_body(
    const unsigned int* __restrict__ ypA, const float* __restrict__ y2A,
    const int* __restrict__ meta1,
    const unsigned int* __restrict__ eas1, const unsigned int* __restrict__ wep1,
    const int* __restrict__ st1, float* __restrict__ xo1,
    unsigned short* __restrict__ xoh1,
    const unsigned int* __restrict__ ypB, const float* __restrict__ y2B,
    const int* __restrict__ meta2,
    const unsigned int* __restrict__ eas2, const unsigned int* __restrict__ wep2,
    const int* __restrict__ st2, float* __restrict__ xo2,
    unsigned short* __restrict__ xoh2)
{
  const unsigned int* yp; const float* y2; const int* meta;
  const unsigned int* eas; const unsigned int* wep; const int* st;
  float* xo; unsigned short* xoh;
  if (blockIdx.z == 0) { yp = ypA; y2 = y2A; meta = meta1; eas = eas1; wep = wep1; st = st1; xo = xo1; xoh = xoh1; }
  else                 { yp = ypB; y2 = y2B; meta = meta2; eas = eas2; wep = wep2; st = st2; xo = xo2; xoh = xoh2; }

  __shared__ unsigned int ypk[4160];   // 16.6 KB: [node][j] stride 65,
                                       // dword j = h2(y[dbase+j], y[dbase+j+64]) fp16
  const int g = blockIdx.x >> 1;
  const int dbase = (blockIdx.x & 1) * 128;
  const int hb = (blockIdx.x & 1);     // dbase half index
  const int tid = threadIdx.x;
  const int l = tid & 63;
  const int w = tid >> 6;       // wave owns nodes [8w, 8w+8)
  const int rh = l & 15;        // MFMA row/col lane coord
  const int qh = l >> 4;        // k-group 0..3
  const int rhw = w * 8 + rh;   // node id matched by indicator row rh

  // ---- stage message half: straight copy of pre-packed pair-dwords ----
  for (int i = tid; i < 4096; i += 512) {
    int n = i >> 6, j = i & 63;
    ypk[n * 65 + j] = yp[(size_t)(g * 64 + n) * 128 + hb * 64 + j];
  }

  // ---- B fragments (We, fp16): lane holds B[k=4qh..4qh+3][col=c*16+rh] ----
  uint2 bfr[8];
#pragma unroll
  for (int c = 0; c < 8; ++c) {
    int d = dbase + c * 16 + rh;
    bfr[c].x = wep[(2 * qh) * 256 + d];
    bfr[c].y = wep[(2 * qh + 1) * 256 + d];
  }

  __syncthreads();

  const int estart = st[g * 65 + w * 8];
  const int eend   = st[g * 65 + w * 8 + 8];

  f32x4 acc[8];
#pragma unroll
  for (int i = 0; i < 8; ++i) acc[i] = (f32x4){0.f, 0.f, 0.f, 0.f};

  // ---- prefetch round 0 (mv masked to -1 for padding lanes) ----
  int base = estart;
  uint2 af = {0u, 0u};
  int mv = -1;
  if (base < eend) {
    int lim = eend - base; if (lim > 16) lim = 16;
    af = *(const uint2*)(eas + ((size_t)g * 2048 + base + (rh < lim ? rh : lim - 1)) * 8 + 2 * qh);
    int m = meta[(size_t)g * 2048 + base + (l < lim ? l : lim - 1)];
    mv = (l < lim) ? m : -1;
  }

  while (base < eend) {
    // ---- pull the 4 metas this lane needs (edges 4qh..4qh+3) ----
    int mp[4];
#pragma unroll
    for (int v = 0; v < 4; ++v)
      mp[v] = __builtin_amdgcn_ds_bpermute(qh * 16 + v * 4, mv);

    // ---- prefetch next round under this round's compute ----
    int nbase = base + 16;
    uint2 afn = af;
    int mvn = -1;
    if (nbase < eend) {
      int nlim = eend - nbase; if (nlim > 16) nlim = 16;
      afn = *(const uint2*)(eas + ((size_t)g * 2048 + nbase + (rh < nlim ? rh : nlim - 1)) * 8 + 2 * qh);
      int m2 = meta[(size_t)g * 2048 + nbase + (l < nlim ? l : nlim - 1)];
      mvn = (l < nlim) ? m2 : -1;
    }

    // ---- MFMA#1: ea@We -> pa (dims c*16+rh), pb (dims 64+c*16+rh) ----
    half4_t afh = __builtin_bit_cast(half4_t, af);
    f32x4 pa[4], pb[4];
#pragma unroll
    for (int cp = 0; cp < 4; ++cp) {
      f32x4 z = (f32x4){0.f, 0.f, 0.f, 0.f};
      pa[cp] = MFMA16F16(afh, __builtin_bit_cast(half4_t, bfr[cp]), z, 0, 0, 0);
      pb[cp] = MFMA16F16(afh, __builtin_bit_cast(half4_t, bfr[cp + 4]), z, 0, 0, 0);
    }

    // ---- y gather + indicator fragments ----
    unsigned int yv[4][4];
    unsigned int ind[4];
#pragma unroll
    for (int v = 0; v < 4; ++v) {
      int sv = mp[v] & 63;
      int dv = (mp[v] >> 8) & 255;          // padding -> 255, never matches
      const unsigned int* yb = ypk + sv * 65 + rh;
      yv[0][v] = yb[0];
      yv[1][v] = yb[16];
      yv[2][v] = yb[32];
      yv[3][v] = yb[48];
      ind[v] = (dv == rhw) ? 0x3C00u : 0u;  // f16 1.0 : 0.0
    }
    uint2 su;
    su.x = ind[0] | (ind[1] << 16);
    su.y = ind[2] | (ind[3] << 16);
    half4_t sfrag = __builtin_bit_cast(half4_t, su);

    // ---- msg = pk_max(pk_add(cvt_pkrtz(pa,pb), y), 0); perm-regroup;
    //      MFMA#2 accumulates segment-sum ----
    const h2v hz = {(_Float16)0.0f, (_Float16)0.0f};
#pragma unroll
    for (int cp = 0; cp < 4; ++cp) {
      unsigned int t[4];
#pragma unroll
      for (int v = 0; v < 4; ++v) {
        h2v s = __builtin_bit_cast(h2v, pack_h2_fast(pa[cp][v], pb[cp][v]));
        s = s + __builtin_bit_cast(h2v, yv[cp][v]);      // v_pk_add_f16
        s = __builtin_elementwise_max(s, hz);            // v_pk_max_f16
        t[v] = __builtin_bit_cast(unsigned int, s);
      }
      uint2 blo, bhi;
      blo.x = __builtin_amdgcn_perm(t[1], t[0], 0x05040100u);
      blo.y = __builtin_amdgcn_perm(t[3], t[2], 0x05040100u);
      bhi.x = __builtin_amdgcn_perm(t[1], t[0], 0x07060302u);
      bhi.y = __builtin_amdgcn_perm(t[3], t[2], 0x07060302u);
      acc[cp]     = MFMA16F16(sfrag, __builtin_bit_cast(half4_t, blo), acc[cp], 0, 0, 0);
      acc[cp + 4] = MFMA16F16(sfrag, __builtin_bit_cast(half4_t, bhi), acc[cp + 4], 0, 0, 0);
    }

    base = nbase;
    af = afn;
    mv = mvn;
  }

  // ---- epilogue: D2 rows 0..7 live in lanes qh<2 (row=4qh+v, col=rh) ----
  if (qh < 2) {
#pragma unroll
    for (int v = 0; v < 4; ++v) {
      int node = g * 64 + w * 8 + qh * 4 + v;
      const float* ysp = y2 + (size_t)node * 256 + dbase + rh;
      float* xop = xo + (size_t)node * 256 + dbase + rh;
      unsigned short* xohp = xoh + (size_t)node * 256 + dbase + rh;
#pragma unroll
      for (int cp = 0; cp < 8; ++cp) {
        int dim = (cp & 3) * 16 + (cp >> 2) * 64;
        float val = fmaxf(ysp[dim] + acc[cp][v], 0.f);
        if (WR32) xop[dim] = val;
        xohp[dim] = f2bf(val);
      }
    }
  }
}

__global__ __launch_bounds__(512, 4) void edge_conv_dual_wf(
    const unsigned int* __restrict__ ypA, const float* __restrict__ y2A,
    const int* __restrict__ meta1,
    const unsigned int* __restrict__ eas1, const unsigned int* __restrict__ wep1,
    const int* __restrict__ st1, float* __restrict__ xo1,
    unsigned short* __restrict__ xoh1,
    const unsigned int* __restrict__ ypB, const float* __restrict__ y2B,
    const int* __restrict__ meta2,
    const unsigned int* __restrict__ eas2, const unsigned int* __restrict__ wep2,
    const int* __restrict__ st2, float* __restrict__ xo2,
    unsigned short* __restrict__ xoh2)
{
  edge_conv_body<true>(ypA, y2A, meta1, eas1, wep1, st1, xo1, xoh1,
                       ypB, y2B, meta2, eas2, wep2, st2, xo2, xoh2);
}

__global__ __launch_bounds__(512, 4) void edge_conv_dual_nf(
    const unsigned int* __restrict__ ypA, const float* __restrict__ y2A,
    const int* __restrict__ meta1,
    const unsigned int* __restrict__ eas1, const unsigned int* __restrict__ wep1,
    const int* __restrict__ st1, float* __restrict__ xo1,
    unsigned short* __restrict__ xoh1,
    const unsigned int* __restrict__ ypB, const float* __restrict__ y2B,
    const int* __restrict__ meta2,
    const unsigned int* __restrict__ eas2, const unsigned int* __restrict__ wep2,
    const int* __restrict__ st2, float* __restrict__ xo2,
    unsigned short* __restrict__ xoh2)
{
  edge_conv_body<false>(ypA, y2A, meta1, eas1, wep1, st1, xo1, xoh1,
                        ypB, y2B, meta2, eas2, wep2, st2, xo2, xoh2);
}

// ---------------------------------------------------------------------------
// dot_pool v2: per graph, item = X1 @ X2^T [64x64] on the matrix pipe from
// the bf16 twins. One block/graph; 64KB LDS, chunk-XOR swizzle (2-way = free).
// ---------------------------------------------------------------------------
__global__ __launch_bounds__(256) void dot_pool_mfma(
    const unsigned short* __restrict__ x1h, const unsigned short* __restrict__ x2h,
    float* __restrict__ fusion, int step)
{
  __shared__ unsigned short s1[64][256];
  __shared__ unsigned short s2[64][256];
  const int g = blockIdx.x, tid = threadIdx.x;
  const int l = tid & 63, w = tid >> 6;
  const int r = l & 15, q = l >> 4;

  for (int i = tid; i < 2048; i += 256) {
    int row = i >> 5, c = i & 31;
    int cs = c ^ (row & 7);
    *(uint4*)&s1[row][cs * 8] = *(const uint4*)(x1h + (size_t)(g * 64 + row) * 256 + c * 8);
    *(uint4*)&s2[row][cs * 8] = *(const uint4*)(x2h + (size_t)(g * 64 + row) * 256 + c * 8);
  }
  __syncthreads();

  const int m0 = w * 16;
  const int sx = r & 7;
  f32x4 acc[4];
#pragma unroll
  for (int nt = 0; nt < 4; ++nt) acc[nt] = (f32x4){0.f, 0.f, 0.f, 0.f};

#pragma unroll
  for (int kb = 0; kb < 32; kb += 4) {     // 8 K-chunks of 32 (4 x 8-ushort)
    int ch = (kb + q) ^ sx;
    short8_t af = *(const short8_t*)&s1[m0 + r][ch * 8];
#pragma unroll
    for (int nt = 0; nt < 4; ++nt) {
      short8_t bf = *(const short8_t*)&s2[nt * 16 + r][ch * 8];
      acc[nt] = __builtin_amdgcn_mfma_f32_16x16x32_bf16(af, bf, acc[nt], 0, 0, 0);
    }
  }

  float mymax = -1e30f, mysum = 0.f;
#pragma unroll
  for (int nt = 0; nt < 4; ++nt)
#pragma unroll
    for (int reg = 0; reg < 4; ++reg) {
      float v = acc[nt][reg];
      mymax = fmaxf(mymax, v);
      mysum += v;
    }
  for (int off = 32; off; off >>= 1) {
    mymax = fmaxf(mymax, __shfl_down(mymax, off, 64));
    mysum += __shfl_down(mysum, off, 64);
  }
  __syncthreads();                       // LDS reads done; reuse s1 as scratch
  float* red = (float*)&s1[0][0];
  if (l == 0) { red[w] = mymax; red[8 + w] = mysum; }
  __syncthreads();
  if (tid == 0) {
    float gm = fmaxf(fmaxf(red[0], red[1]), fmaxf(red[2], red[3]));
    float gs = red[8] + red[9] + red[10] + red[11];
    fusion[g * 6 + step * 2] = gm;
    fusion[g * 6 + step * 2 + 1] = gs * (1.f / 4096.f);
  }
}

// ---------------------------------------------------------------------------
// readout (dual, grid 512): R[g] = [mean | sum | top3-by-last-col rows]
// ---------------------------------------------------------------------------
__global__ __launch_bounds__(256) void readout_dual(
    const float* __restrict__ xm1, const float* __restrict__ xm2,
    float* __restrict__ R1, float* __restrict__ R2)
{
  const int mol = blockIdx.x >> 8;
  const float* xm = mol ? xm2 : xm1;
  float* R = mol ? R2 : R1;
  __shared__ float lastcol[64];
  __shared__ int topi[3];
  const int g = blockIdx.x & 255, d = threadIdx.x;
  float s = 0.f;
  for (int n = 0; n < 64; ++n) s += xm[(size_t)(g * 64 + n) * 256 + d];
  R[(size_t)g * 1280 + d] = s * (1.f / 64.f);
  R[(size_t)g * 1280 + 256 + d] = s;
  if (d < 64) lastcol[d] = xm[(size_t)(g * 64 + d) * 256 + 255];
  __syncthreads();
  if (d == 0) {
    unsigned long long used = 0;
    for (int j = 0; j < 3; ++j) {
      float best = -1e30f;
      int bi = 0;
      for (int n = 0; n < 64; ++n) {
        if ((used >> n) & 1ull) continue;
        if (lastcol[n] > best) { best = lastcol[n]; bi = n; }
      }
      used |= (1ull << bi);
      topi[j] = bi;
    }
  }
  __syncthreads();
  for (int j = 0; j < 3; ++j)
    R[(size_t)g * 1280 + 512 + j * 256 + d] =
        xm[(size_t)(g * 64 + topi[j]) * 256 + d];
}

// ---------------------------------------------------------------------------
// final head: cat = [sum_k P1[k] + bf1 | sum_k P2[k] + bf2 | fusion];
// out = (cat @ Wo1 + bo1) @ Wo2 + bo2
// ---------------------------------------------------------------------------
__global__ __launch_bounds__(256) void final_head(
    const float* __restrict__ P1, const float* __restrict__ P2,
    const float* __restrict__ bf1, const float* __restrict__ bf2,
    const float* __restrict__ fusion,
    const float* __restrict__ Wo1, const float* __restrict__ bo1,
    const float* __restrict__ Wo2, const float* __restrict__ bo2,
    float* __restrict__ out)
{
  __shared__ float cat[520];
  __shared__ float r0s[4], r1s[4];
  const int g = blockIdx.x, t = threadIdx.x;
  float s1 = bf1[t], s2 = bf2[t];
#pragma unroll
  for (int k = 0; k < NKSPLIT; ++k) {
    s1 += P1[((size_t)k * 256 + g) * 256 + t];
    s2 += P2[((size_t)k * 256 + g) * 256 + t];
  }
  cat[t] = s1;
  cat[256 + t] = s2;
  if (t < 6) cat[512 + t] = fusion[g * 6 + t];
  __syncthreads();
  float a0 = 0.f, a1 = 0.f, a2 = 0.f, a3 = 0.f;
  for (int k = 0; k < 516; k += 4) {
    a0 = fmaf(cat[k],     Wo1[(size_t)(k)     * 256 + t], a0);
    a1 = fmaf(cat[k + 1], Wo1[(size_t)(k + 1) * 256 + t], a1);
    a2 = fmaf(cat[k + 2], Wo1[(size_t)(k + 2) * 256 + t], a2);
    a3 = fmaf(cat[k + 3], Wo1[(size_t)(k + 3) * 256 + t], a3);
  }
  a0 = fmaf(cat[516], Wo1[(size_t)516 * 256 + t], a0);
  a1 = fmaf(cat[517], Wo1[(size_t)517 * 256 + t], a1);
  float acc = bo1[t] + ((a0 + a1) + (a2 + a3));
  float p0 = acc * Wo2[t * 2];
  float p1 = acc * Wo2[t * 2 + 1];
  for (int off = 32; off; off >>= 1) {
    p0 += __shfl_down(p0, off, 64);
    p1 += __shfl_down(p1, off, 64);
  }
  if ((t & 63) == 0) { r0s[t >> 6] = p0; r1s[t >> 6] = p1; }
  __syncthreads();
  if (t == 0) {
    out[g * 2] = r0s[0] + r0s[1] + r0s[2] + r0s[3] + bo2[0];
    out[g * 2 + 1] = r1s[0] + r1s[1] + r1s[2] + r1s[3] + bo2[1];
  }
}

// ---------------------------------------------------------------------------
// Weight transposes, recoalesced: LDS tile per 64-k-row slab, coalesced
// fp32 reads and uint4 bf16 writes. Grid 60.
// ---------------------------------------------------------------------------
__global__ __launch_bounds__(256) void transpose_all(
    const float* __restrict__ W0_1, const float* __restrict__ W0_2,
    const float* __restrict__ Wn1, const float* __restrict__ Ws1,
    const float* __restrict__ Wn2, const float* __restrict__ Ws2,
    const float* __restrict__ Wf1, const float* __restrict__ Wf2,
    unsigned short* __restrict__ W0T1, unsigned short* __restrict__ W0T2,
    unsigned short* __restrict__ WcT1, unsigned short* __restrict__ WcT2,
    unsigned short* __restrict__ WfT1, unsigned short* __restrict__ WfT2)
{
  const int b = blockIdx.x;
  const float* src; unsigned short* dst; int k0, K;
  if (b < 2)       { src = W0_1; dst = W0T1;         K = 128;  k0 = b * 64; }
  else if (b < 4)  { src = W0_2; dst = W0T2;         K = 128;  k0 = (b - 2) * 64; }
  else if (b < 8)  { src = Wn1;  dst = WcT1;         K = 256;  k0 = (b - 4) * 64; }
  else if (b < 12) { src = Ws1;  dst = WcT1 + 65536; K = 256;  k0 = (b - 8) * 64; }
  else if (b < 16) { src = Wn2;  dst = WcT2;         K = 256;  k0 = (b - 12) * 64; }
  else if (b < 20) { src = Ws2;  dst = WcT2 + 65536; K = 256;  k0 = (b - 16) * 64; }
  else if (b < 40) { src = Wf1;  dst = WfT1;         K = 1280; k0 = (b - 20) * 64; }
  else             { src = Wf2;  dst = WfT2;         K = 1280; k0 = (b - 40) * 64; }

  __shared__ unsigned short t[64][258];
  const int tid = threadIdx.x;
  for (int i = tid; i < 16384; i += 256) {
    int row = i >> 8, col = i & 255;
    t[row][col] = f2bf(src[(size_t)(k0 + row) * 256 + col]);
  }
  __syncthreads();
  unsigned short* dp = dst + (size_t)tid * K + k0;
  for (int k = 0; k < 64; k += 8) {
    uint4 v;
    v.x = (unsigned)t[k + 0][tid] | ((unsigned)t[k + 1][tid] << 16);
    v.y = (unsigned)t[k + 2][tid] | ((unsigned)t[k + 3][tid] << 16);
    v.z = (unsigned)t[k + 4][tid] | ((unsigned)t[k + 5][tid] << 16);
    v.w = (unsigned)t[k + 6][tid] | ((unsigned)t[k + 7][tid] << 16);
    *(uint4*)(dp + k) = v;
  }
}

__global__ void misc_prep(
    const float* bm1, const float* bs1, const float* bm2, const float* bs2,
    const float* We1, const float* We2,
    float* bcat1, float* bcat2,
    unsigned int* weh1, unsigned int* weh2)
{
  int idx = blockIdx.x * 256 + threadIdx.x;  // grid 20 -> 5120
  if (idx < 512) {
    bcat1[idx] = idx < 256 ? bm1[idx] : bs1[idx - 256];
  } else if (idx < 1024) {
    int i = idx - 512;
    bcat2[i] = i < 256 ? bm2[i] : bs2[i - 256];
  } else if (idx < 3072) {
    int i = idx - 1024, j = i >> 8, d = i & 255;
    weh1[i] = pack_h2(We1[(2 * j) * 256 + d], We1[(2 * j + 1) * 256 + d]);
  } else if (idx < 5120) {
    int i = idx - 3072, j = i >> 8, d = i & 255;
    weh2[i] = pack_h2(We2[(2 * j) * 256 + d], We2[(2 * j + 1) * 256 + d]);
  }
}

// ---------------------------------------------------------------------------
extern "C" void kernel_launch(void* const* d_in, const int* in_sizes, int n_in,
                              void* d_out, int out_size, void* d_ws, size_t ws_size,
                              hipStream_t stream)
{
  const float* x1 = (const float*)d_in[0];
  const int* ei1 = (const int*)d_in[1];
  const float* ea1 = (const float*)d_in[2];
  const float* x2 = (const float*)d_in[4];
  const int* ei2 = (const int*)d_in[5];
  const float* ea2 = (const float*)d_in[6];
  const float* W0_1 = (const float*)d_in[8];
  const float* b0_1 = (const float*)d_in[9];
  const float* W0_2 = (const float*)d_in[10];
  const float* b0_2 = (const float*)d_in[11];
  const float* Wn1 = (const float*)d_in[12];
  const float* We1 = (const float*)d_in[13];
  const float* bm1 = (const float*)d_in[14];
  const float* Ws1 = (const float*)d_in[15];
  const float* bs1 = (const float*)d_in[16];
  const float* Wn2 = (const float*)d_in[17];
  const float* We2 = (const float*)d_in[18];
  const float* bm2 = (const float*)d_in[19];
  const float* Ws2 = (const float*)d_in[20];
  const float* bs2 = (const float*)d_in[21];
  const float* Wf1 = (const float*)d_in[22];
  const float* bf1 = (const float*)d_in[23];
  const float* Wf2 = (const float*)d_in[24];
  const float* bf2 = (const float*)d_in[25];
  const float* Wo1 = (const float*)d_in[26];
  const float* bo1 = (const float*)d_in[27];
  const float* Wo2 = (const float*)d_in[28];
  const float* bo2 = (const float*)d_in[29];
  float* out = (float*)d_out;

  float* w = (float*)d_ws;
  size_t off = 0;
  auto alloc = [&](size_t nf) { float* p = w + off; off += nf; return p; };
  float* xmA1 = alloc(4194304);
  float* xmA2 = alloc(4194304);
  float* xmB1 = alloc(4194304);
  float* xmB2 = alloc(4194304);
  unsigned int* yp1 = (unsigned int*)alloc(2097152);
  unsigned int* yp2 = (unsigned int*)alloc(2097152);
  float* y2a1 = alloc(4194304);
  float* y2a2 = alloc(4194304);
  float* R1 = alloc(327680);
  float* R2 = alloc(327680);
  float* P1 = alloc(655360);
  float* P2 = alloc(655360);
  float* fusion = alloc(1536);
  float* bcat1 = alloc(512);
  float* bcat2 = alloc(512);
  unsigned short* W0T1 = (unsigned short*)alloc(16384);
  unsigned short* W0T2 = (unsigned short*)alloc(16384);
  unsigned short* WcT1 = (unsigned short*)alloc(65536);
  unsigned short* WcT2 = (unsigned short*)alloc(65536);
  unsigned short* WfT1 = (unsigned short*)alloc(163840);
  unsigned short* WfT2 = (unsigned short*)alloc(163840);
  unsigned int* weh1 = (unsigned int*)alloc(2048);
  unsigned int* weh2 = (unsigned int*)alloc(2048);
  unsigned int* eah1 = (unsigned int*)alloc(4194304);
  unsigned int* eah2 = (unsigned int*)alloc(4194304);
  int* meta1 = (int*)alloc(524288);
  int* meta2 = (int*)alloc(524288);
  int* starts1 = (int*)alloc(16640);
  int* starts2 = (int*)alloc(16640);
  unsigned short* xmhA1 = (unsigned short*)alloc(2097152);
  unsigned short* xmhA2 = (unsigned short*)alloc(2097152);
  unsigned short* xmhB1 = (unsigned short*)alloc(2097152);
  unsigned short* xmhB2 = (unsigned short*)alloc(2097152);
  (void)in_sizes; (void)n_in; (void)out_size; (void)ws_size;

  // ---- prep (ea gather+pack fused into the sort) ----
  sort_edges_dual<<<512, 256, 0, stream>>>(ei1, ei2, ea1, ea2,
                                           meta1, meta2, eah1, eah2,
                                           starts1, starts2);
  transpose_all<<<60, 256, 0, stream>>>(W0_1, W0_2, Wn1, Ws1, Wn2, Ws2,
                                        Wf1, Wf2, W0T1, W0T2, WcT1, WcT2,
                                        WfT1, WfT2);
  misc_prep<<<20, 256, 0, stream>>>(bm1, bs1, bm2, bs2, We1, We2,
                                    bcat1, bcat2, weh1, weh2);

  // ---- embed: xmh = bf16(rrelu(x @ W0 + b0)) ----
  gemm_bf16_dual<<<dim3(128, 2, 2), 256, 0, stream>>>(
      x1, W0T1, b0_1, nullptr, xmhA1, x2, W0T2, b0_2, nullptr, xmhA2,
      128, 256, 128, 2);

  // ---- 3 message-passing steps ----
  float* cur1 = xmA1; float* cur2 = xmA2;
  float* nxt1 = xmB1; float* nxt2 = xmB2;
  unsigned short* curh1 = xmhA1; unsigned short* curh2 = xmhA2;
  unsigned short* nxth1 = xmhB1; unsigned short* nxth2 = xmhB2;
  for (int step = 0; step < 3; ++step) {
    gemm_h_dual<<<dim3(128, 4, 2), 256, 0, stream>>>(
        curh1, WcT1, bcat1, yp1, y2a1, curh2, WcT2, bcat2, yp2, y2a2, 256);
    if (step == 2) {
      edge_conv_dual_wf<<<dim3(512, 1, 2), 512, 0, stream>>>(
          yp1, y2a1, meta1, eah1, weh1, starts1, nxt1, nxth1,
          yp2, y2a2, meta2, eah2, weh2, starts2, nxt2, nxth2);
    } else {
      edge_conv_dual_nf<<<dim3(512, 1, 2), 512, 0, stream>>>(
          yp1, y2a1, meta1, eah1, weh1, starts1, nxt1, nxth1,
          yp2, y2a2, meta2, eah2, weh2, starts2, nxt2, nxth2);
    }
    dot_pool_mfma<<<256, 256, 0, stream>>>(nxth1, nxth2, fusion, step);
    float* t1 = cur1; cur1 = nxt1; nxt1 = t1;
    float* t2 = cur2; cur2 = nxt2; nxt2 = t2;
    unsigned short* th1 = curh1; curh1 = nxth1; nxth1 = th1;
    unsigned short* th2 = curh2; curh2 = nxth2; nxth2 = th2;
  }

  // ---- readout + split-K head GEMM + final head ----
  readout_dual<<<512, 256, 0, stream>>>(cur1, cur2, R1, R2);
  gemm_splitk_dual<<<dim3(4, 4, 2 * NKSPLIT), 256, 0, stream>>>(
      R1, WfT1, P1, R2, WfT2, P2);
  final_head<<<256, 256, 0, stream>>>(P1, P2, bf1, bf2, fusion,
                                      Wo1, bo1, Wo2, bo2, out);
}